// Round 7
// baseline (206.604 us; speedup 1.0000x reference)
//
#include <hip/hip_runtime.h>
#include <math.h>

#define BATCH    65536
#define FEAT     512
#define NCLASS   16
#define LAMDA    1.0f
#define LAMDA1   10.0f
#define SCALE    1.0f
#define EPS      1e-9f

constexpr int BLOCK  = 256;
constexpr int GRID   = 4096;
constexpr int NV     = BATCH * (FEAT / 4);     // 8,388,608 float4 elements
constexpr int STRIDE = GRID * BLOCK;           // 1,048,576
constexpr int ITERS  = NV / STRIDE;            // exactly 8

typedef float f4v    __attribute__((ext_vector_type(4)));
typedef int   int32x4 __attribute__((ext_vector_type(4)));

// Raw buffer load with explicit cache-policy bits (robust extern-asm binding
// to the LLVM intrinsic; works across ROCm versions).
extern "C" __device__ f4v
llvm_amdgcn_raw_buffer_load_v4f32(int32x4 rsrc, int voffset, int soffset, int aux)
    __asm("llvm.amdgcn.raw.buffer.load.v4f32");

// gfx940+/gfx950 CPol bits: sc0=1, nt=2, sc1=16.
// sc0|nt|sc1 = 19: no L1 allocate, non-temporal, coherence-point scope
// (no L2 allocate). Theory: the ~2.6 TB/s structure-invariant cap on the x
// stream is the per-XCD L2 miss/allocate port (~128 B/cyc * 8 XCD * 2.4 GHz
// = 2.46 TB/s); bypassing L2 allocation should lift it.
#define AUX_STREAM 19

// ---------------------------------------------------------------------------
// Kernel 1: center-loss partial sums. No atomics (R5 win), y hoisted to
// s_loads, x via sc1-streaming buffer loads, centers via normal cached loads.
// ---------------------------------------------------------------------------
__global__ __launch_bounds__(BLOCK) void center_loss_kernel(
    const float* __restrict__ x,        // [BATCH * FEAT]
    const int*   __restrict__ y,        // [BATCH]
    const f4v*   __restrict__ centers4, // [NCLASS * FEAT/4]
    float*       __restrict__ partials) // ws: [GRID], one slot per block
{
    const int tid = blockIdx.x * BLOCK + threadIdx.x;

    // wave-uniform sample-row base (wave = 64 consecutive tid inside one
    // 128-aligned chunk; STRIDE % 128 == 0) -> y loads become s_loads.
    const int base_b = __builtin_amdgcn_readfirstlane(tid >> 7);
    const int d4     = tid & 127;

    // Buffer resource for x: base, num_records = full byte size, raw dword.
    int32x4 rsrc;
    rsrc.x = (int)(size_t)x;
    rsrc.y = (int)((size_t)x >> 32);
    rsrc.z = NV * 16;            // bytes
    rsrc.w = 0x00020000;

    // Hoist all 8 class ids out of the main loop.
    int cls[ITERS];
    #pragma unroll
    for (int it = 0; it < ITERS; ++it)
        cls[it] = y[base_b + it * (STRIDE >> 7)];

    float sum = 0.0f;
    #pragma unroll
    for (int it = 0; it < ITERS; ++it) {
        f4v xv = llvm_amdgcn_raw_buffer_load_v4f32(
            rsrc, (tid + it * STRIDE) * 16, 0, AUX_STREAM);
        f4v cv = centers4[cls[it] * (FEAT / 4) + d4];   // cache-hot gather
        f4v e  = xv - cv;
        sum += e.x * e.x + e.y * e.y + e.z * e.z + e.w * e.w;
    }

    // wave (64-lane) shuffle reduction
    #pragma unroll
    for (int off = 32; off > 0; off >>= 1)
        sum += __shfl_down(sum, off, 64);

    __shared__ float wsum[4];
    const int lane = threadIdx.x & 63;
    const int wid  = threadIdx.x >> 6;
    if (lane == 0) wsum[wid] = sum;
    __syncthreads();
    if (threadIdx.x == 0) {
        partials[blockIdx.x] = wsum[0] + wsum[1] + wsum[2] + wsum[3];
    }
}

// ---------------------------------------------------------------------------
// Kernel 2 (single block): reduce 4096 partials + 16x16 gram + combine.
// ---------------------------------------------------------------------------
__global__ __launch_bounds__(256) void finalize_kernel(
    const f4v*   __restrict__ centers4, // [NCLASS * FEAT/4]
    const float* __restrict__ partials, // [GRID]
    float*       __restrict__ out)      // [1]
{
    // ---- reduce the 4096 per-block partials (16 per thread, coalesced) ----
    float psum = 0.0f;
    #pragma unroll
    for (int k = 0; k < GRID / 256; ++k)
        psum += partials[threadIdx.x + k * 256];
    #pragma unroll
    for (int off = 32; off > 0; off >>= 1)
        psum += __shfl_down(psum, off, 64);

    __shared__ float wsum[4];
    const int lane = threadIdx.x & 63;
    const int wid  = threadIdx.x >> 6;
    if (lane == 0) wsum[wid] = psum;

    // ---- 16x16 gram from L2-hot centers ----
    __shared__ float gram[NCLASS][NCLASS];
    const int j = threadIdx.x >> 4;
    const int k = threadIdx.x & 15;
    const f4v* cj = centers4 + j * (FEAT / 4);
    const f4v* ck = centers4 + k * (FEAT / 4);
    float dot = 0.0f;
    #pragma unroll 8
    for (int i = 0; i < FEAT / 4; ++i) {
        f4v a = cj[i];
        f4v b = ck[i];
        dot += a.x * b.x + a.y * b.y + a.z * b.z + a.w * b.w;
    }
    gram[j][k] = dot;
    __syncthreads();

    if (threadIdx.x == 0) {
        float item1 = 0.0f;
        for (int jj = 0; jj < NCLASS; ++jj) {
            float nj = sqrtf(gram[jj][jj]);
            for (int kk = jj + 1; kk < NCLASS; ++kk) {
                float nk = sqrtf(gram[kk][kk]);
                item1 += gram[jj][kk] / (nj * nk + EPS) + 1.0f;
            }
        }
        float total = wsum[0] + wsum[1] + wsum[2] + wsum[3];
        float loss_center = 0.5f * total * (SCALE / (float)BATCH);
        out[0] = LAMDA * (loss_center + LAMDA1 * item1);
    }
}

extern "C" void kernel_launch(void* const* d_in, const int* in_sizes, int n_in,
                              void* d_out, int out_size, void* d_ws, size_t ws_size,
                              hipStream_t stream) {
    const float* x       = (const float*)d_in[0];   // [BATCH, FEAT]
    const int*   y       = (const int*)d_in[1];     // [BATCH]
    const float* centers = (const float*)d_in[2];   // [NCLASS, FEAT]
    float* out      = (float*)d_out;
    float* partials = (float*)d_ws;                 // 4096 floats, all written

    center_loss_kernel<<<GRID, BLOCK, 0, stream>>>(
        x, y, (const f4v*)centers, partials);

    finalize_kernel<<<1, 256, 0, stream>>>((const f4v*)centers, partials, out);
}